// Round 1
// baseline (517.524 us; speedup 1.0000x reference)
//
#include <hip/hip_runtime.h>
#include <math.h>

#define NB 8192
#define ND 256
#define NSJ 16                 // j-range splits
#define JSLICE (NB / NSJ)      // 512
#define TI 128
#define TJ 128
#define KB 16
#define MARGIN_F 0.3f
#define EPS_F 1e-6f

// ---------------- squared norms: one wave per row ----------------
__global__ __launch_bounds__(64) void norms_k(const float* __restrict__ emb,
                                              float* __restrict__ sqn) {
    const int row = blockIdx.x;
    const int lane = threadIdx.x;
    const float4 v = *reinterpret_cast<const float4*>(&emb[(size_t)row * ND + lane * 4]);
    float s = v.x * v.x + v.y * v.y + v.z * v.z + v.w * v.w;
#pragma unroll
    for (int m = 32; m; m >>= 1) s += __shfl_down(s, m, 64);
    if (lane == 0) sqn[row] = s;
}

// ---------------- fused pairwise-dist + hardest mining ----------------
// grid (NB/TI, NSJ); block 256 = 16x16 threads, 8x8 micro-tile each.
__global__ __launch_bounds__(256, 2) void pair_k(
        const float* __restrict__ emb, const float* __restrict__ sqn,
        const int* __restrict__ labels,
        float* __restrict__ pos_val, int* __restrict__ pos_idx,
        float* __restrict__ neg_val, int* __restrict__ neg_idx,
        int* __restrict__ flags) {
    __shared__ float As[KB][TI];
    __shared__ float Bs[KB][TJ];
    __shared__ float sqj_s[TJ];
    __shared__ int   lbl_s[TJ];

    const int tid = threadIdx.x;
    const int tx = tid & 15;
    const int ty = tid >> 4;
    const int i_base = blockIdx.x * TI;
    const int slice = blockIdx.y;

    float sqi[8]; int li[8];
    float bpv[8]; int bpi[8];
    float bnv[8]; int bni[8];
    int hasp = 0, hasn = 0;
#pragma unroll
    for (int a = 0; a < 8; ++a) {
        const int i = i_base + ty * 8 + a;
        sqi[a] = sqn[i];
        li[a]  = labels[i];
        bpv[a] = 0.0f;      bpi[a] = 0;   // matches argmax(all-zeros)=0 semantics
        bnv[a] = INFINITY;  bni[a] = 0;
    }

    for (int jt = slice * JSLICE; jt < (slice + 1) * JSLICE; jt += TJ) {
        __syncthreads();  // prev epilogue done reading sqj_s/lbl_s
        if (tid < TJ) sqj_s[tid] = sqn[jt + tid];
        else          lbl_s[tid - TJ] = labels[jt + tid - TJ];

        float acc[8][8];
#pragma unroll
        for (int a = 0; a < 8; ++a)
#pragma unroll
            for (int b = 0; b < 8; ++b) acc[a][b] = 0.0f;

        for (int kt = 0; kt < ND; kt += KB) {
            __syncthreads();  // reads of previous kt (and sqj staging) done
#pragma unroll
            for (int l = 0; l < 2; ++l) {
                const int f = l * 256 + tid;      // 0..511, bijective (row,seg)
                const int row = f >> 2;           // 0..127
                const int seg = f & 3;            // 0..3
                const float4 va = *reinterpret_cast<const float4*>(
                    &emb[(size_t)(i_base + row) * ND + kt + seg * 4]);
                As[seg * 4 + 0][row] = va.x; As[seg * 4 + 1][row] = va.y;
                As[seg * 4 + 2][row] = va.z; As[seg * 4 + 3][row] = va.w;
                const float4 vb = *reinterpret_cast<const float4*>(
                    &emb[(size_t)(jt + row) * ND + kt + seg * 4]);
                Bs[seg * 4 + 0][row] = vb.x; Bs[seg * 4 + 1][row] = vb.y;
                Bs[seg * 4 + 2][row] = vb.z; Bs[seg * 4 + 3][row] = vb.w;
            }
            __syncthreads();
#pragma unroll
            for (int k = 0; k < KB; ++k) {
                const float4 a0 = *reinterpret_cast<const float4*>(&As[k][ty * 8]);
                const float4 a1 = *reinterpret_cast<const float4*>(&As[k][ty * 8 + 4]);
                const float4 b0 = *reinterpret_cast<const float4*>(&Bs[k][tx * 8]);
                const float4 b1 = *reinterpret_cast<const float4*>(&Bs[k][tx * 8 + 4]);
                const float av[8] = {a0.x, a0.y, a0.z, a0.w, a1.x, a1.y, a1.z, a1.w};
                const float bv[8] = {b0.x, b0.y, b0.z, b0.w, b1.x, b1.y, b1.z, b1.w};
#pragma unroll
                for (int a = 0; a < 8; ++a)
#pragma unroll
                    for (int b = 0; b < 8; ++b)
                        acc[a][b] = fmaf(av[a], bv[b], acc[a][b]);
            }
        }

        // epilogue: masked running argmax/argmin (j ascending -> strict cmp = first-occurrence)
#pragma unroll
        for (int a = 0; a < 8; ++a) {
            const int ii = i_base + ty * 8 + a;
            const float si = sqi[a];
            const int la = li[a];
#pragma unroll
            for (int b = 0; b < 8; ++b) {
                const int jj = jt + tx * 8 + b;
                const float d = fmaxf(si + sqj_s[tx * 8 + b] - 2.0f * acc[a][b], 0.0f);
                const bool same = (lbl_s[tx * 8 + b] == la);
                if (same) {
                    if (jj != ii) {
                        hasp |= 1 << a;
                        if (d > bpv[a]) { bpv[a] = d; bpi[a] = jj; }
                    }
                } else {
                    hasn |= 1 << a;
                    if (d < bnv[a]) { bnv[a] = d; bni[a] = jj; }
                }
            }
        }
    }

    // reduce across the 16 tx lanes (tie -> smaller index = first occurrence)
#pragma unroll
    for (int m = 1; m < 16; m <<= 1) {
        hasp |= __shfl_xor(hasp, m, 64);
        hasn |= __shfl_xor(hasn, m, 64);
    }
    for (int a = 0; a < 8; ++a) {
        float pv = bpv[a]; int pi = bpi[a];
        float nv = bnv[a]; int ni = bni[a];
#pragma unroll
        for (int m = 1; m < 16; m <<= 1) {
            const float pv2 = __shfl_xor(pv, m, 64); const int pi2 = __shfl_xor(pi, m, 64);
            if (pv2 > pv || (pv2 == pv && pi2 < pi)) { pv = pv2; pi = pi2; }
            const float nv2 = __shfl_xor(nv, m, 64); const int ni2 = __shfl_xor(ni, m, 64);
            if (nv2 < nv || (nv2 == nv && ni2 < ni)) { nv = nv2; ni = ni2; }
        }
        if (tx == 0) {
            const int i = i_base + ty * 8 + a;
            const size_t o = (size_t)slice * NB + i;
            pos_val[o] = pv; pos_idx[o] = pi;
            neg_val[o] = nv; neg_idx[o] = ni;
            flags[o] = ((hasp >> a) & 1) | (((hasn >> a) & 1) << 1);
        }
    }
}

// ---------------- per-anchor finalize: slice-reduce + gather + hinge ----------------
__global__ __launch_bounds__(256) void finalize_k(
        const float* __restrict__ emb,
        const float* __restrict__ pos_val, const int* __restrict__ pos_idx,
        const float* __restrict__ neg_val, const int* __restrict__ neg_idx,
        const int* __restrict__ flags,
        float* __restrict__ per_anc, float* __restrict__ validf) {
    const int w = threadIdx.x >> 6;
    const int lane = threadIdx.x & 63;
    const int i = blockIdx.x * 4 + w;

    const int s = lane & 15;
    const size_t o = (size_t)s * NB + i;
    float pv = pos_val[o]; int pi = pos_idx[o];
    float nv = neg_val[o]; int ni = neg_idx[o];
    int fl = flags[o];
#pragma unroll
    for (int m = 1; m < 16; m <<= 1) {
        const float pv2 = __shfl_xor(pv, m, 64); const int pi2 = __shfl_xor(pi, m, 64);
        if (pv2 > pv || (pv2 == pv && pi2 < pi)) { pv = pv2; pi = pi2; }
        const float nv2 = __shfl_xor(nv, m, 64); const int ni2 = __shfl_xor(ni, m, 64);
        if (nv2 < nv || (nv2 == nv && ni2 < ni)) { nv = nv2; ni = ni2; }
        fl |= __shfl_xor(fl, m, 64);
    }

    const float4 av  = *reinterpret_cast<const float4*>(&emb[(size_t)i  * ND + lane * 4]);
    const float4 pvv = *reinterpret_cast<const float4*>(&emb[(size_t)pi * ND + lane * 4]);
    const float4 nvv = *reinterpret_cast<const float4*>(&emb[(size_t)ni * ND + lane * 4]);
    float sap, san;
    {
        const float d0 = av.x - pvv.x + EPS_F, d1 = av.y - pvv.y + EPS_F;
        const float d2 = av.z - pvv.z + EPS_F, d3 = av.w - pvv.w + EPS_F;
        sap = d0 * d0 + d1 * d1 + d2 * d2 + d3 * d3;
        const float e0 = av.x - nvv.x + EPS_F, e1 = av.y - nvv.y + EPS_F;
        const float e2 = av.z - nvv.z + EPS_F, e3 = av.w - nvv.w + EPS_F;
        san = e0 * e0 + e1 * e1 + e2 * e2 + e3 * e3;
    }
#pragma unroll
    for (int m = 32; m; m >>= 1) {
        sap += __shfl_down(sap, m, 64);
        san += __shfl_down(san, m, 64);
    }
    if (lane == 0) {
        const bool valid = (fl & 3) == 3;
        const float per = fmaxf(sqrtf(sap) - sqrtf(san) + MARGIN_F, 0.0f);
        per_anc[i] = valid ? per : 0.0f;
        validf[i]  = valid ? 1.0f : 0.0f;
    }
}

// ---------------- final mean ----------------
__global__ __launch_bounds__(256) void reduce_k(const float* __restrict__ per_anc,
                                                const float* __restrict__ validf,
                                                float* __restrict__ out) {
    __shared__ float ss[4], sc[4];
    float s = 0.0f, c = 0.0f;
    for (int i = threadIdx.x; i < NB; i += 256) { s += per_anc[i]; c += validf[i]; }
#pragma unroll
    for (int m = 32; m; m >>= 1) { s += __shfl_down(s, m, 64); c += __shfl_down(c, m, 64); }
    const int w = threadIdx.x >> 6, lane = threadIdx.x & 63;
    if (lane == 0) { ss[w] = s; sc[w] = c; }
    __syncthreads();
    if (threadIdx.x == 0) {
        const float S = ss[0] + ss[1] + ss[2] + ss[3];
        const float C = sc[0] + sc[1] + sc[2] + sc[3];
        out[0] = (C > 0.0f) ? (S / fmaxf(C, 1.0f)) : 0.0f;
    }
}

extern "C" void kernel_launch(void* const* d_in, const int* in_sizes, int n_in,
                              void* d_out, int out_size, void* d_ws, size_t ws_size,
                              hipStream_t stream) {
    const float* emb = (const float*)d_in[0];
    const int* labels = (const int*)d_in[1];
    float* out = (float*)d_out;

    float* ws = (float*)d_ws;
    float* sqn     = ws;                 // NB
    float* per_anc = ws + NB;            // NB
    float* validf  = ws + 2 * NB;        // NB
    float* pos_val = ws + 3 * NB;        // NSJ*NB
    int*   pos_idx = (int*)(pos_val + (size_t)NSJ * NB);
    float* neg_val = (float*)(pos_idx + (size_t)NSJ * NB);
    int*   neg_idx = (int*)(neg_val + (size_t)NSJ * NB);
    int*   flags   = (int*)(neg_idx + (size_t)NSJ * NB);

    hipLaunchKernelGGL(norms_k, dim3(NB), dim3(64), 0, stream, emb, sqn);
    hipLaunchKernelGGL(pair_k, dim3(NB / TI, NSJ), dim3(256), 0, stream,
                       emb, sqn, labels, pos_val, pos_idx, neg_val, neg_idx, flags);
    hipLaunchKernelGGL(finalize_k, dim3(NB / 4), dim3(256), 0, stream,
                       emb, pos_val, pos_idx, neg_val, neg_idx, flags, per_anc, validf);
    hipLaunchKernelGGL(reduce_k, dim3(1), dim3(256), 0, stream, per_anc, validf, out);
}

// Round 2
// 331.902 us; speedup vs baseline: 1.5593x; 1.5593x over previous
//
#include <hip/hip_runtime.h>
#include <math.h>

#define NB 8192
#define ND 256
#define NSJ 16
#define JSLICE (NB / NSJ)      // 512
#define TI 128
#define TJ 128
#define BK 32
#define NPART (NSJ * 2)        // two col-halves per slice
#define MARGIN_F 0.3f
#define EPS_F 1e-6f

typedef __attribute__((ext_vector_type(8))) short bf16x8;
typedef __attribute__((ext_vector_type(4))) float f32x4;

__device__ __forceinline__ unsigned short f2bf(float x) {
    unsigned int u = __float_as_uint(x);
    return (unsigned short)((u + 0x7fffu + ((u >> 16) & 1u)) >> 16);
}
__device__ __forceinline__ float bf2f(unsigned short h) {
    return __uint_as_float(((unsigned int)h) << 16);
}

__device__ __forceinline__ void gld16(const void* g, void* l) {
    __builtin_amdgcn_global_load_lds(
        (const __attribute__((address_space(1))) void*)g,
        (__attribute__((address_space(3))) void*)l, 16, 0, 0);
}

// ---------------- fp32 -> (bf16 hi, bf16 lo) split ----------------
__global__ __launch_bounds__(256) void conv_k(const float* __restrict__ emb,
                                              unsigned short* __restrict__ ehi,
                                              unsigned short* __restrict__ elo) {
    const int idx = (blockIdx.x * 256 + threadIdx.x) * 4;
    const float4 v = *reinterpret_cast<const float4*>(&emb[idx]);
    ushort4 h, l;
    h.x = f2bf(v.x); l.x = f2bf(v.x - bf2f(h.x));
    h.y = f2bf(v.y); l.y = f2bf(v.y - bf2f(h.y));
    h.z = f2bf(v.z); l.z = f2bf(v.z - bf2f(h.z));
    h.w = f2bf(v.w); l.w = f2bf(v.w - bf2f(h.w));
    *reinterpret_cast<ushort4*>(&ehi[idx]) = h;
    *reinterpret_cast<ushort4*>(&elo[idx]) = l;
}

// ---------------- squared norms: one wave per row ----------------
__global__ __launch_bounds__(64) void norms_k(const float* __restrict__ emb,
                                              float* __restrict__ sqn) {
    const int row = blockIdx.x;
    const int lane = threadIdx.x;
    const float4 v = *reinterpret_cast<const float4*>(&emb[(size_t)row * ND + lane * 4]);
    float s = v.x * v.x + v.y * v.y + v.z * v.z + v.w * v.w;
#pragma unroll
    for (int m = 32; m; m >>= 1) s += __shfl_down(s, m, 64);
    if (lane == 0) sqn[row] = s;
}

// ---------------- MFMA pairwise + hardest mining ----------------
// grid (NB/TI, NSJ); block 256 = 4 waves; wave w: rows (w&1)*64, cols (w>>1)*64.
__global__ __launch_bounds__(256, 2) void pair_k(
        const unsigned short* __restrict__ ehi, const unsigned short* __restrict__ elo,
        const float* __restrict__ sqn, const int* __restrict__ labels,
        float* __restrict__ pos_val, int* __restrict__ pos_idx,
        float* __restrict__ neg_val, int* __restrict__ neg_idx,
        int* __restrict__ flags) {
    __shared__ short Ash[8 * 512];   // 8 subtiles x (16 rows x 32 k)
    __shared__ short Asl[8 * 512];
    __shared__ short Bsh[8 * 512];
    __shared__ short Bsl[8 * 512];
    __shared__ float sqj_s[TJ];
    __shared__ int   lbl_j_s[TJ];
    __shared__ int   lbl_i_s[TI];

    const int tid  = threadIdx.x;
    const int w    = tid >> 6;
    const int lane = tid & 63;
    const int q    = lane >> 4;
    const int lx   = lane & 15;
    const int i_base = blockIdx.x * TI;
    const int slice  = blockIdx.y;
    const int wr = (w & 1) * 64;     // wave row base in tile
    const int wc = (w >> 1) * 64;    // wave col base in tile
    const int sa_base = (w & 1) * 4; // A subtile base
    const int sb_base = (w >> 1) * 4;

    if (tid < TI) lbl_i_s[tid] = labels[i_base + tid];

    float Ppv = -INFINITY; int Ppi = 0;
    float Pnv =  INFINITY; int Pni = 0;
    int Pfl = 0;

    for (int jb = slice * JSLICE; jb < (slice + 1) * JSLICE; jb += TJ) {
        __syncthreads();   // prev epilogue done reading sqj_s/lbl_j_s
        if (tid < TJ) sqj_s[tid] = sqn[jb + tid];
        else          lbl_j_s[tid - TJ] = labels[jb + tid - TJ];

        f32x4 acc[4][4];
#pragma unroll
        for (int a = 0; a < 4; ++a)
#pragma unroll
            for (int b = 0; b < 4; ++b) acc[a][b] = (f32x4){0.f, 0.f, 0.f, 0.f};

        for (int k0 = 0; k0 < ND; k0 += BK) {
            __syncthreads();   // prev frag reads done; sqj stage visible
            // wave w stages matrix w (Ahi/Alo/Bhi/Blo), 8 subtiles of 1 KB
            {
                const unsigned short* src = (w == 0 || w == 2) ? ehi : elo;
                short* dstb = (w == 0) ? Ash : (w == 1) ? Asl : (w == 2) ? Bsh : Bsl;
                const int grow0 = (w < 2) ? i_base : jb;
#pragma unroll
                for (int m = 0; m < 8; ++m) {
                    const unsigned short* g =
                        src + (size_t)(grow0 + m * 16 + lx) * ND + k0 + q * 8;
                    gld16(g, dstb + m * 512);
                }
            }
            __syncthreads();   // staging complete (vmcnt drained by barrier)

            bf16x8 ah[4], al[4], bh[4], bl[4];
#pragma unroll
            for (int t = 0; t < 4; ++t) {
                ah[t] = *(const bf16x8*)&Ash[(sa_base + t) * 512 + lane * 8];
                al[t] = *(const bf16x8*)&Asl[(sa_base + t) * 512 + lane * 8];
                bh[t] = *(const bf16x8*)&Bsh[(sb_base + t) * 512 + lane * 8];
                bl[t] = *(const bf16x8*)&Bsl[(sb_base + t) * 512 + lane * 8];
            }
#pragma unroll
            for (int tr = 0; tr < 4; ++tr)
#pragma unroll
                for (int tc = 0; tc < 4; ++tc) {
                    acc[tr][tc] = __builtin_amdgcn_mfma_f32_16x16x32_bf16(
                        ah[tr], bh[tc], acc[tr][tc], 0, 0, 0);
                    acc[tr][tc] = __builtin_amdgcn_mfma_f32_16x16x32_bf16(
                        ah[tr], bl[tc], acc[tr][tc], 0, 0, 0);
                    acc[tr][tc] = __builtin_amdgcn_mfma_f32_16x16x32_bf16(
                        al[tr], bh[tc], acc[tr][tc], 0, 0, 0);
                }
        }

        // epilogue: mining on v = |e_j|^2 - 2*dot (row-constant |e_i|^2 dropped)
        // C layout: row = q*4 + reg, col = lx (within 16x16 tile)
#pragma unroll
        for (int tr = 0; tr < 4; ++tr) {
#pragma unroll
            for (int reg = 0; reg < 4; ++reg) {
                const int rowb = wr + tr * 16 + q * 4 + reg;
                const int ii = i_base + rowb;
                const int la = lbl_i_s[rowb];
                float pv = -INFINITY; int pi = 0;
                float nv =  INFINITY; int ni = 0;
                int hp = 0, hn = 0;
#pragma unroll
                for (int tc = 0; tc < 4; ++tc) {
                    const int colb = wc + tc * 16 + lx;
                    const int jj = jb + colb;
                    const float v = sqj_s[colb] - 2.0f * acc[tr][tc][reg];
                    if (lbl_j_s[colb] == la) {
                        if (jj != ii) { hp = 1; if (v > pv) { pv = v; pi = jj; } }
                    } else {
                        hn = 1; if (v < nv) { nv = v; ni = jj; }
                    }
                }
                const unsigned long long bp = __ballot(hp);
                const unsigned long long bn = __ballot(hn);
#pragma unroll
                for (int mm = 1; mm < 16; mm <<= 1) {
                    const float pv2 = __shfl_xor(pv, mm, 64);
                    const int   pi2 = __shfl_xor(pi, mm, 64);
                    if (pv2 > pv || (pv2 == pv && pi2 < pi)) { pv = pv2; pi = pi2; }
                    const float nv2 = __shfl_xor(nv, mm, 64);
                    const int   ni2 = __shfl_xor(ni, mm, 64);
                    if (nv2 < nv || (nv2 == nv && ni2 < ni)) { nv = nv2; ni = ni2; }
                }
                if (lx == tr * 4 + reg) {
                    const int ghp = ((bp >> (q * 16)) & 0xffffull) != 0;
                    const int ghn = ((bn >> (q * 16)) & 0xffffull) != 0;
                    if (ghp) { Pfl |= 1; if (pv > Ppv || (pv == Ppv && pi < Ppi)) { Ppv = pv; Ppi = pi; } }
                    if (ghn) { Pfl |= 2; if (nv < Pnv || (nv == Pnv && ni < Pni)) { Pnv = nv; Pni = ni; } }
                }
            }
        }
    }

    // lane (lx, q) owns row: tr = lx>>2, reg = lx&3
    const int rowb = wr + ((lx >> 2) * 16) + q * 4 + (lx & 3);
    const size_t o = (size_t)(slice * 2 + (w >> 1)) * NB + i_base + rowb;
    pos_val[o] = Ppv; pos_idx[o] = Ppi;
    neg_val[o] = Pnv; neg_idx[o] = Pni;
    flags[o] = Pfl;
}

// ---------------- per-anchor finalize: partial-reduce + gather + hinge ----------------
__global__ __launch_bounds__(256) void finalize_k(
        const float* __restrict__ emb,
        const float* __restrict__ pos_val, const int* __restrict__ pos_idx,
        const float* __restrict__ neg_val, const int* __restrict__ neg_idx,
        const int* __restrict__ flags,
        float* __restrict__ per_anc, float* __restrict__ validf) {
    const int w = threadIdx.x >> 6;
    const int lane = threadIdx.x & 63;
    const int i = blockIdx.x * 4 + w;

    const int s = lane & 31;
    const size_t o = (size_t)s * NB + i;
    float pv = pos_val[o]; int pi = pos_idx[o];
    float nv = neg_val[o]; int ni = neg_idx[o];
    int fl = flags[o];
#pragma unroll
    for (int mm = 1; mm < 32; mm <<= 1) {
        const float pv2 = __shfl_xor(pv, mm, 64); const int pi2 = __shfl_xor(pi, mm, 64);
        if (pv2 > pv || (pv2 == pv && pi2 < pi)) { pv = pv2; pi = pi2; }
        const float nv2 = __shfl_xor(nv, mm, 64); const int ni2 = __shfl_xor(ni, mm, 64);
        if (nv2 < nv || (nv2 == nv && ni2 < ni)) { nv = nv2; ni = ni2; }
        fl |= __shfl_xor(fl, mm, 64);
    }

    const float4 av  = *reinterpret_cast<const float4*>(&emb[(size_t)i  * ND + lane * 4]);
    const float4 pvv = *reinterpret_cast<const float4*>(&emb[(size_t)pi * ND + lane * 4]);
    const float4 nvv = *reinterpret_cast<const float4*>(&emb[(size_t)ni * ND + lane * 4]);
    float sap, san;
    {
        const float d0 = av.x - pvv.x + EPS_F, d1 = av.y - pvv.y + EPS_F;
        const float d2 = av.z - pvv.z + EPS_F, d3 = av.w - pvv.w + EPS_F;
        sap = d0 * d0 + d1 * d1 + d2 * d2 + d3 * d3;
        const float e0 = av.x - nvv.x + EPS_F, e1 = av.y - nvv.y + EPS_F;
        const float e2 = av.z - nvv.z + EPS_F, e3 = av.w - nvv.w + EPS_F;
        san = e0 * e0 + e1 * e1 + e2 * e2 + e3 * e3;
    }
#pragma unroll
    for (int m = 32; m; m >>= 1) {
        sap += __shfl_down(sap, m, 64);
        san += __shfl_down(san, m, 64);
    }
    if (lane == 0) {
        const bool valid = (fl & 3) == 3;
        const float per = fmaxf(sqrtf(sap) - sqrtf(san) + MARGIN_F, 0.0f);
        per_anc[i] = valid ? per : 0.0f;
        validf[i]  = valid ? 1.0f : 0.0f;
    }
}

// ---------------- final mean ----------------
__global__ __launch_bounds__(256) void reduce_k(const float* __restrict__ per_anc,
                                                const float* __restrict__ validf,
                                                float* __restrict__ out) {
    __shared__ float ss[4], sc[4];
    float s = 0.0f, c = 0.0f;
    for (int i = threadIdx.x; i < NB; i += 256) { s += per_anc[i]; c += validf[i]; }
#pragma unroll
    for (int m = 32; m; m >>= 1) { s += __shfl_down(s, m, 64); c += __shfl_down(c, m, 64); }
    const int w = threadIdx.x >> 6, lane = threadIdx.x & 63;
    if (lane == 0) { ss[w] = s; sc[w] = c; }
    __syncthreads();
    if (threadIdx.x == 0) {
        const float S = ss[0] + ss[1] + ss[2] + ss[3];
        const float C = sc[0] + sc[1] + sc[2] + sc[3];
        out[0] = (C > 0.0f) ? (S / fmaxf(C, 1.0f)) : 0.0f;
    }
}

extern "C" void kernel_launch(void* const* d_in, const int* in_sizes, int n_in,
                              void* d_out, int out_size, void* d_ws, size_t ws_size,
                              hipStream_t stream) {
    const float* emb = (const float*)d_in[0];
    const int* labels = (const int*)d_in[1];
    float* out = (float*)d_out;

    char* ws = (char*)d_ws;
    unsigned short* ehi = (unsigned short*)ws;                         // 4 MB
    unsigned short* elo = (unsigned short*)(ws + (size_t)NB * ND * 2); // 4 MB
    float* sqn     = (float*)(ws + (size_t)NB * ND * 4);
    float* per_anc = sqn + NB;
    float* validf  = per_anc + NB;
    float* pos_val = validf + NB;                                  // NPART*NB
    int*   pos_idx = (int*)(pos_val + (size_t)NPART * NB);
    float* neg_val = (float*)(pos_idx + (size_t)NPART * NB);
    int*   neg_idx = (int*)(neg_val + (size_t)NPART * NB);
    int*   flags   = (int*)(neg_idx + (size_t)NPART * NB);

    hipLaunchKernelGGL(conv_k, dim3(NB * ND / 1024), dim3(256), 0, stream, emb, ehi, elo);
    hipLaunchKernelGGL(norms_k, dim3(NB), dim3(64), 0, stream, emb, sqn);
    hipLaunchKernelGGL(pair_k, dim3(NB / TI, NSJ), dim3(256), 0, stream,
                       ehi, elo, sqn, labels, pos_val, pos_idx, neg_val, neg_idx, flags);
    hipLaunchKernelGGL(finalize_k, dim3(NB / 4), dim3(256), 0, stream,
                       emb, pos_val, pos_idx, neg_val, neg_idx, flags, per_anc, validf);
    hipLaunchKernelGGL(reduce_k, dim3(1), dim3(256), 0, stream, per_anc, validf, out);
}

// Round 3
// 200.756 us; speedup vs baseline: 2.5779x; 1.6533x over previous
//
#include <hip/hip_runtime.h>
#include <math.h>

#define NB 8192
#define ND 256
#define NSJ 16
#define JSLICE (NB / NSJ)      // 512
#define TI 128
#define TJ 128
#define BK 32
#define NPART (NSJ * 2)        // two col-halves per slice
#define MARGIN_F 0.3f
#define EPS_F 1e-6f

typedef __attribute__((ext_vector_type(8))) short bf16x8;
typedef __attribute__((ext_vector_type(4))) float f32x4;

__device__ __forceinline__ unsigned short f2bf(float x) {
    unsigned int u = __float_as_uint(x);
    return (unsigned short)((u + 0x7fffu + ((u >> 16) & 1u)) >> 16);
}

__device__ __forceinline__ void gld16(const void* g, void* l) {
    __builtin_amdgcn_global_load_lds(
        (const __attribute__((address_space(1))) void*)g,
        (__attribute__((address_space(3))) void*)l, 16, 0, 0);
}

// ---------------- fused: fp32 -> bf16(hi) pre-packed in MFMA-fragment order, + sq norms ----
// Packed layout: tile_id = (row>>4)*8 + (k>>5); elem = lane*8+j where lane=((k>>3)&3)*16+(row&15).
// Block: 512 threads = 16 rows x full K. Write is perfectly coalesced: ehi + blk*4096 + tid*8.
__global__ __launch_bounds__(512) void prep_k(const float* __restrict__ emb,
                                              unsigned short* __restrict__ ehi,
                                              float* __restrict__ sqn) {
    __shared__ float sm[8][16];
    const int tid = threadIdx.x;
    const int tk = tid >> 6;          // k-tile 0..7
    const int lane = tid & 63;
    const int q = lane >> 4;          // k-chunk in tile
    const int lx = lane & 15;         // row in 16-group
    const int row = blockIdx.x * 16 + lx;
    const int k = tk * 32 + q * 8;

    const float4 v0 = *reinterpret_cast<const float4*>(&emb[(size_t)row * ND + k]);
    const float4 v1 = *reinterpret_cast<const float4*>(&emb[(size_t)row * ND + k + 4]);
    ushort4 h0, h1;
    h0.x = f2bf(v0.x); h0.y = f2bf(v0.y); h0.z = f2bf(v0.z); h0.w = f2bf(v0.w);
    h1.x = f2bf(v1.x); h1.y = f2bf(v1.y); h1.z = f2bf(v1.z); h1.w = f2bf(v1.w);
    *reinterpret_cast<ushort4*>(&ehi[(size_t)blockIdx.x * 4096 + tid * 8])     = h0;
    *reinterpret_cast<ushort4*>(&ehi[(size_t)blockIdx.x * 4096 + tid * 8 + 4]) = h1;

    float s = v0.x * v0.x + v0.y * v0.y + v0.z * v0.z + v0.w * v0.w
            + v1.x * v1.x + v1.y * v1.y + v1.z * v1.z + v1.w * v1.w;
    s += __shfl_xor(s, 16, 64);
    s += __shfl_xor(s, 32, 64);       // lanes with same lx now hold per-wave row partial
    if (q == 0) sm[tk][lx] = s;
    __syncthreads();
    if (tid < 16) {
        float t = 0.0f;
#pragma unroll
        for (int wv = 0; wv < 8; ++wv) t += sm[wv][tid];
        sqn[blockIdx.x * 16 + tid] = t;
    }
}

// ---------------- MFMA pairwise + hardest mining (hi-only) ----------------
// grid (NB/TI, NSJ); block 256 = 4 waves; wave w: rows (w&1)*64, cols (w>>1)*64.
__global__ __launch_bounds__(256, 4) void pair_k(
        const unsigned short* __restrict__ ehi,
        const float* __restrict__ sqn, const int* __restrict__ labels,
        float* __restrict__ pos_val, int* __restrict__ pos_idx,
        float* __restrict__ neg_val, int* __restrict__ neg_idx,
        int* __restrict__ flags) {
    __shared__ short Ash[8 * 512];   // 8 subtiles x (16 rows x 32 k), fragment order
    __shared__ short Bsh[8 * 512];
    __shared__ float sqj_s[TJ];
    __shared__ int   lbl_j_s[TJ];
    __shared__ int   lbl_i_s[TI];

    const int tid  = threadIdx.x;
    const int w    = tid >> 6;
    const int lane = tid & 63;
    const int q    = lane >> 4;
    const int lx   = lane & 15;
    const int i_base = blockIdx.x * TI;
    const int slice  = blockIdx.y;
    const int wr = (w & 1) * 64;
    const int wc = (w >> 1) * 64;
    const int sa_base = (w & 1) * 4;
    const int sb_base = (w >> 1) * 4;
    const int ib16 = i_base >> 4;

    if (tid < TI) lbl_i_s[tid] = labels[i_base + tid];

    float Ppv = -INFINITY; int Ppi = 0;
    float Pnv =  INFINITY; int Pni = 0;
    int Pfl = 0;

    for (int jb = slice * JSLICE; jb < (slice + 1) * JSLICE; jb += TJ) {
        __syncthreads();   // prev epilogue done reading sqj_s/lbl_j_s
        if (tid < TJ) sqj_s[tid] = sqn[jb + tid];
        else          lbl_j_s[tid - TJ] = labels[jb + tid - TJ];
        const int jb16 = jb >> 4;

        f32x4 acc[4][4];
#pragma unroll
        for (int a = 0; a < 4; ++a)
#pragma unroll
            for (int b = 0; b < 4; ++b) acc[a][b] = (f32x4){0.f, 0.f, 0.f, 0.f};

        for (int k0 = 0; k0 < ND; k0 += BK) {
            const int kb = k0 >> 5;
            __syncthreads();   // prev frag reads done; sqj stage visible downstream
            // waves 0,1 stage A subtiles, waves 2,3 stage B subtiles (coalesced 1KB each)
            {
                const int half = (w & 1) * 4;
                const int gb16 = (w < 2) ? ib16 : jb16;
                short* dst = (w < 2) ? Ash : Bsh;
#pragma unroll
                for (int m2 = 0; m2 < 4; ++m2) {
                    const int m = half + m2;
                    const unsigned short* g =
                        ehi + ((size_t)(gb16 + m) * 8 + kb) * 512 + lane * 8;
                    gld16(g, dst + m * 512);
                }
            }
            __syncthreads();   // staging complete

            bf16x8 ah[4], bh[4];
#pragma unroll
            for (int t = 0; t < 4; ++t) {
                ah[t] = *(const bf16x8*)&Ash[(sa_base + t) * 512 + lane * 8];
                bh[t] = *(const bf16x8*)&Bsh[(sb_base + t) * 512 + lane * 8];
            }
#pragma unroll
            for (int tr = 0; tr < 4; ++tr)
#pragma unroll
                for (int tc = 0; tc < 4; ++tc)
                    acc[tr][tc] = __builtin_amdgcn_mfma_f32_16x16x32_bf16(
                        ah[tr], bh[tc], acc[tr][tc], 0, 0, 0);
        }

        // epilogue: mining on v = |e_j|^2 - 2*dot (row-constant |e_i|^2 dropped)
        // C layout: row = q*4 + reg, col = lx (within each 16x16 tile)
#pragma unroll
        for (int tr = 0; tr < 4; ++tr) {
#pragma unroll
            for (int reg = 0; reg < 4; ++reg) {
                const int rowb = wr + tr * 16 + q * 4 + reg;
                const int ii = i_base + rowb;
                const int la = lbl_i_s[rowb];
                float pv = -INFINITY; int pi = 0;
                float nv =  INFINITY; int ni = 0;
                int hp = 0, hn = 0;
#pragma unroll
                for (int tc = 0; tc < 4; ++tc) {
                    const int colb = wc + tc * 16 + lx;
                    const int jj = jb + colb;
                    const float v = sqj_s[colb] - 2.0f * acc[tr][tc][reg];
                    if (lbl_j_s[colb] == la) {
                        if (jj != ii) { hp = 1; if (v > pv) { pv = v; pi = jj; } }
                    } else {
                        hn = 1; if (v < nv) { nv = v; ni = jj; }
                    }
                }
                const unsigned long long bp = __ballot(hp);
                const unsigned long long bn = __ballot(hn);
#pragma unroll
                for (int mm = 1; mm < 16; mm <<= 1) {
                    const float pv2 = __shfl_xor(pv, mm, 64);
                    const int   pi2 = __shfl_xor(pi, mm, 64);
                    if (pv2 > pv || (pv2 == pv && pi2 < pi)) { pv = pv2; pi = pi2; }
                    const float nv2 = __shfl_xor(nv, mm, 64);
                    const int   ni2 = __shfl_xor(ni, mm, 64);
                    if (nv2 < nv || (nv2 == nv && ni2 < ni)) { nv = nv2; ni = ni2; }
                }
                if (lx == tr * 4 + reg) {
                    const int ghp = ((bp >> (q * 16)) & 0xffffull) != 0;
                    const int ghn = ((bn >> (q * 16)) & 0xffffull) != 0;
                    if (ghp) { Pfl |= 1; if (pv > Ppv || (pv == Ppv && pi < Ppi)) { Ppv = pv; Ppi = pi; } }
                    if (ghn) { Pfl |= 2; if (nv < Pnv || (nv == Pnv && ni < Pni)) { Pnv = nv; Pni = ni; } }
                }
            }
        }
    }

    // lane (lx, q) owns row: tr = lx>>2, reg = lx&3
    const int rowb = wr + ((lx >> 2) * 16) + q * 4 + (lx & 3);
    const size_t o = (size_t)(slice * 2 + (w >> 1)) * NB + i_base + rowb;
    pos_val[o] = Ppv; pos_idx[o] = Ppi;
    neg_val[o] = Pnv; neg_idx[o] = Pni;
    flags[o] = Pfl;
}

// ---------------- per-anchor finalize: partial-reduce + exact gather + hinge ----------------
__global__ __launch_bounds__(256) void finalize_k(
        const float* __restrict__ emb,
        const float* __restrict__ pos_val, const int* __restrict__ pos_idx,
        const float* __restrict__ neg_val, const int* __restrict__ neg_idx,
        const int* __restrict__ flags,
        float* __restrict__ per_anc, float* __restrict__ validf) {
    const int w = threadIdx.x >> 6;
    const int lane = threadIdx.x & 63;
    const int i = blockIdx.x * 4 + w;

    const int s = lane & 31;
    const size_t o = (size_t)s * NB + i;
    float pv = pos_val[o]; int pi = pos_idx[o];
    float nv = neg_val[o]; int ni = neg_idx[o];
    int fl = flags[o];
#pragma unroll
    for (int mm = 1; mm < 32; mm <<= 1) {
        const float pv2 = __shfl_xor(pv, mm, 64); const int pi2 = __shfl_xor(pi, mm, 64);
        if (pv2 > pv || (pv2 == pv && pi2 < pi)) { pv = pv2; pi = pi2; }
        const float nv2 = __shfl_xor(nv, mm, 64); const int ni2 = __shfl_xor(ni, mm, 64);
        if (nv2 < nv || (nv2 == nv && ni2 < ni)) { nv = nv2; ni = ni2; }
        fl |= __shfl_xor(fl, mm, 64);
    }

    const float4 av  = *reinterpret_cast<const float4*>(&emb[(size_t)i  * ND + lane * 4]);
    const float4 pvv = *reinterpret_cast<const float4*>(&emb[(size_t)pi * ND + lane * 4]);
    const float4 nvv = *reinterpret_cast<const float4*>(&emb[(size_t)ni * ND + lane * 4]);
    float sap, san;
    {
        const float d0 = av.x - pvv.x + EPS_F, d1 = av.y - pvv.y + EPS_F;
        const float d2 = av.z - pvv.z + EPS_F, d3 = av.w - pvv.w + EPS_F;
        sap = d0 * d0 + d1 * d1 + d2 * d2 + d3 * d3;
        const float e0 = av.x - nvv.x + EPS_F, e1 = av.y - nvv.y + EPS_F;
        const float e2 = av.z - nvv.z + EPS_F, e3 = av.w - nvv.w + EPS_F;
        san = e0 * e0 + e1 * e1 + e2 * e2 + e3 * e3;
    }
#pragma unroll
    for (int m = 32; m; m >>= 1) {
        sap += __shfl_down(sap, m, 64);
        san += __shfl_down(san, m, 64);
    }
    if (lane == 0) {
        const bool valid = (fl & 3) == 3;
        const float per = fmaxf(sqrtf(sap) - sqrtf(san) + MARGIN_F, 0.0f);
        per_anc[i] = valid ? per : 0.0f;
        validf[i]  = valid ? 1.0f : 0.0f;
    }
}

// ---------------- final mean ----------------
__global__ __launch_bounds__(256) void reduce_k(const float* __restrict__ per_anc,
                                                const float* __restrict__ validf,
                                                float* __restrict__ out) {
    __shared__ float ss[4], sc[4];
    float s = 0.0f, c = 0.0f;
    for (int i = threadIdx.x; i < NB; i += 256) { s += per_anc[i]; c += validf[i]; }
#pragma unroll
    for (int m = 32; m; m >>= 1) { s += __shfl_down(s, m, 64); c += __shfl_down(c, m, 64); }
    const int w = threadIdx.x >> 6, lane = threadIdx.x & 63;
    if (lane == 0) { ss[w] = s; sc[w] = c; }
    __syncthreads();
    if (threadIdx.x == 0) {
        const float S = ss[0] + ss[1] + ss[2] + ss[3];
        const float C = sc[0] + sc[1] + sc[2] + sc[3];
        out[0] = (C > 0.0f) ? (S / fmaxf(C, 1.0f)) : 0.0f;
    }
}

extern "C" void kernel_launch(void* const* d_in, const int* in_sizes, int n_in,
                              void* d_out, int out_size, void* d_ws, size_t ws_size,
                              hipStream_t stream) {
    const float* emb = (const float*)d_in[0];
    const int* labels = (const int*)d_in[1];
    float* out = (float*)d_out;

    char* ws = (char*)d_ws;
    unsigned short* ehi = (unsigned short*)ws;                     // 4 MB, packed
    float* sqn     = (float*)(ws + (size_t)NB * ND * 2);
    float* per_anc = sqn + NB;
    float* validf  = per_anc + NB;
    float* pos_val = validf + NB;                                  // NPART*NB
    int*   pos_idx = (int*)(pos_val + (size_t)NPART * NB);
    float* neg_val = (float*)(pos_idx + (size_t)NPART * NB);
    int*   neg_idx = (int*)(neg_val + (size_t)NPART * NB);
    int*   flags   = (int*)(neg_idx + (size_t)NPART * NB);

    hipLaunchKernelGGL(prep_k, dim3(NB / 16), dim3(512), 0, stream, emb, ehi, sqn);
    hipLaunchKernelGGL(pair_k, dim3(NB / TI, NSJ), dim3(256), 0, stream,
                       ehi, sqn, labels, pos_val, pos_idx, neg_val, neg_idx, flags);
    hipLaunchKernelGGL(finalize_k, dim3(NB / 4), dim3(256), 0, stream,
                       emb, pos_val, pos_idx, neg_val, neg_idx, flags, per_anc, validf);
    hipLaunchKernelGGL(reduce_k, dim3(1), dim3(256), 0, stream, per_anc, validf, out);
}

// Round 4
// 174.852 us; speedup vs baseline: 2.9598x; 1.1481x over previous
//
#include <hip/hip_runtime.h>
#include <math.h>

#define NB 8192
#define ND 256
#define NSJ 8
#define JSLICE (NB / NSJ)      // 1024 cols per block
#define MARGIN_F 0.3f
#define EPS_F 1e-6f
#define BIAS_F 512.0f          // makes v = |e_j|^2 + BIAS - 2*dot strictly positive

typedef __attribute__((ext_vector_type(8))) short bf16x8;
typedef __attribute__((ext_vector_type(4))) float f32x4;

__device__ __forceinline__ unsigned short f2bf(float x) {
    unsigned int u = __float_as_uint(x);
    return (unsigned short)((u + 0x7fffu + ((u >> 16) & 1u)) >> 16);
}

// ---- prep: fp32 -> bf16 packed in MFMA-fragment order, + biased sq norms, + key init ----
// Packed layout: subtile = (row>>4)*8 + (k>>5); within: lane = ((k>>3)&3)*16 + (row&15), 8 bf16.
__global__ __launch_bounds__(512) void prep_k(const float* __restrict__ emb,
                                              unsigned short* __restrict__ ehi,
                                              float* __restrict__ sqnb,
                                              unsigned int* __restrict__ pos_key,
                                              unsigned int* __restrict__ neg_key) {
    __shared__ float sm[8][16];
    const int tid = threadIdx.x;
    const int tk = tid >> 6;          // k-tile 0..7
    const int lane = tid & 63;
    const int q = lane >> 4;
    const int lx = lane & 15;
    const int row = blockIdx.x * 16 + lx;
    const int k = tk * 32 + q * 8;

    const float4 v0 = *reinterpret_cast<const float4*>(&emb[(size_t)row * ND + k]);
    const float4 v1 = *reinterpret_cast<const float4*>(&emb[(size_t)row * ND + k + 4]);
    ushort4 h0, h1;
    h0.x = f2bf(v0.x); h0.y = f2bf(v0.y); h0.z = f2bf(v0.z); h0.w = f2bf(v0.w);
    h1.x = f2bf(v1.x); h1.y = f2bf(v1.y); h1.z = f2bf(v1.z); h1.w = f2bf(v1.w);
    *reinterpret_cast<ushort4*>(&ehi[(size_t)blockIdx.x * 4096 + tid * 8])     = h0;
    *reinterpret_cast<ushort4*>(&ehi[(size_t)blockIdx.x * 4096 + tid * 8 + 4]) = h1;

    // atomic-key init (8192 each over 512 blocks -> 16/block)
    if (tid >= 32 && tid < 48) pos_key[blockIdx.x * 16 + (tid - 32)] = 0u;
    if (tid >= 48 && tid < 64) neg_key[blockIdx.x * 16 + (tid - 48)] = 0xFFFFFFFFu;

    float s = v0.x * v0.x + v0.y * v0.y + v0.z * v0.z + v0.w * v0.w
            + v1.x * v1.x + v1.y * v1.y + v1.z * v1.z + v1.w * v1.w;
    s += __shfl_xor(s, 16, 64);
    s += __shfl_xor(s, 32, 64);
    if (q == 0) sm[tk][lx] = s;
    __syncthreads();
    if (tid < 16) {
        float t = 0.0f;
#pragma unroll
        for (int wv = 0; wv < 8; ++wv) t += sm[wv][tid];
        sqnb[blockIdx.x * 16 + tid] = t + BIAS_F;
    }
}

// ---- per-tile mining epilogue: 7 VALU / element, no cross-lane ops ----
template <bool DIAG>
__device__ __forceinline__ void mine_tile(
        const f32x4 (&acc)[4][4], const float (&sqjc)[4], const int (&lblc)[4],
        const unsigned (&enc)[4], const int (&la)[16],
        unsigned (&pmax)[16], unsigned (&nmin)[16],
        int wr, int wc, int q, int lx) {
#pragma unroll
    for (int tr = 0; tr < 4; ++tr) {
#pragma unroll
        for (int reg = 0; reg < 4; ++reg) {
            const int r = tr * 4 + reg;
            const int rowb = wr + tr * 16 + q * 4 + reg;
            const int lab = la[r];
#pragma unroll
            for (int tc = 0; tc < 4; ++tc) {
                const float v = fmaf(-2.0f, acc[tr][tc][reg], sqjc[tc]);
                const unsigned key = (__float_as_uint(v) & 0xFFFFE000u) | enc[tc];
                const bool same = (lblc[tc] == lab);
                bool pc = same;
                if (DIAG) pc = same && ((wc + tc * 16 + lx) != rowb);
                const unsigned pk = pc ? key : 0u;
                const unsigned nk = same ? 0xFFFFFFFFu : key;
                pmax[r] = pmax[r] >= pk ? pmax[r] : pk;
                nmin[r] = nmin[r] <= nk ? nmin[r] : nk;
            }
        }
    }
}

// ---- MFMA pairwise + hardest mining; no LDS, no barriers ----
// grid (64, NSJ); block 256 = 4 independent waves; wave w: rows (w&1)*64, cols (w>>1)*64.
__global__ __launch_bounds__(256, 2) void pair_k(
        const unsigned short* __restrict__ ehi, const float* __restrict__ sqnb,
        const int* __restrict__ labels,
        unsigned int* __restrict__ pos_key, unsigned int* __restrict__ neg_key) {
    const int tid = threadIdx.x;
    const int w = tid >> 6;
    const int lane = tid & 63;
    const int q = lane >> 4;
    const int lx = lane & 15;
    const int i_base = blockIdx.x * 128;
    const int slice = blockIdx.y;
    const int wr = (w & 1) * 64;
    const int wc = (w >> 1) * 64;
    const size_t a_sub = (size_t)(i_base >> 4) + (w & 1) * 4;

    int la[16];
#pragma unroll
    for (int tr = 0; tr < 4; ++tr)
#pragma unroll
        for (int reg = 0; reg < 4; ++reg)
            la[tr * 4 + reg] = labels[i_base + wr + tr * 16 + q * 4 + reg];

    unsigned pmax[16], nmin[16];
#pragma unroll
    for (int r = 0; r < 16; ++r) { pmax[r] = 0u; nmin[r] = 0xFFFFFFFFu; }

    const bf16x8* __restrict__ eh = (const bf16x8*)ehi;   // 16-byte units

    for (int jt = 0; jt < JSLICE / 128; ++jt) {
        const int jb = slice * JSLICE + jt * 128;
        const size_t b_sub = (size_t)(jb >> 4) + (w >> 1) * 4;

        int lblc[4]; float sqjc[4]; unsigned enc[4];
#pragma unroll
        for (int tc = 0; tc < 4; ++tc) {
            const int colb = wc + tc * 16 + lx;
            lblc[tc] = labels[jb + colb];
            sqjc[tc] = sqnb[jb + colb];
            enc[tc] = 8191u - (unsigned)(jb + colb);
        }

        f32x4 acc[4][4];
#pragma unroll
        for (int a = 0; a < 4; ++a)
#pragma unroll
            for (int b = 0; b < 4; ++b) acc[a][b] = (f32x4){0.f, 0.f, 0.f, 0.f};

        // software-pipelined K-loop: frags straight from L2, no LDS, no barriers
        bf16x8 ab[2][4], bb[2][4];
#pragma unroll
        for (int t = 0; t < 4; ++t) {
            ab[0][t] = eh[((a_sub + t) * 8 + 0) * 64 + lane];
            bb[0][t] = eh[((b_sub + t) * 8 + 0) * 64 + lane];
        }
#pragma unroll
        for (int kb = 0; kb < 8; ++kb) {
            const int cur = kb & 1, nxt = cur ^ 1;
            if (kb < 7) {
#pragma unroll
                for (int t = 0; t < 4; ++t) {
                    ab[nxt][t] = eh[((a_sub + t) * 8 + (kb + 1)) * 64 + lane];
                    bb[nxt][t] = eh[((b_sub + t) * 8 + (kb + 1)) * 64 + lane];
                }
            }
#pragma unroll
            for (int tr = 0; tr < 4; ++tr)
#pragma unroll
                for (int tc = 0; tc < 4; ++tc)
                    acc[tr][tc] = __builtin_amdgcn_mfma_f32_16x16x32_bf16(
                        ab[cur][tr], bb[cur][tc], acc[tr][tc], 0, 0, 0);
        }

        if (jb == i_base)
            mine_tile<true>(acc, sqjc, lblc, enc, la, pmax, nmin, wr, wc, q, lx);
        else
            mine_tile<false>(acc, sqjc, lblc, enc, la, pmax, nmin, wr, wc, q, lx);
    }

    // once-per-kernel cross-lane reduce (within 16-lane groups) + global atomics
#pragma unroll
    for (int r = 0; r < 16; ++r) {
        unsigned pm = pmax[r], nm = nmin[r];
#pragma unroll
        for (int mm = 1; mm < 16; mm <<= 1) {
            const unsigned pm2 = __shfl_xor(pm, mm, 64);
            const unsigned nm2 = __shfl_xor(nm, mm, 64);
            pm = pm >= pm2 ? pm : pm2;
            nm = nm <= nm2 ? nm : nm2;
        }
        if (lx == r) {
            const int row = i_base + wr + (r >> 2) * 16 + q * 4 + (r & 3);
            atomicMax(&pos_key[row], pm);
            atomicMin(&neg_key[row], nm);
        }
    }
}

// ---- finalize: decode keys + exact fp32 gather + hinge ----
__global__ __launch_bounds__(256) void finalize_k(
        const float* __restrict__ emb,
        const unsigned int* __restrict__ pos_key, const unsigned int* __restrict__ neg_key,
        float* __restrict__ per_anc, float* __restrict__ validf) {
    const int w = threadIdx.x >> 6;
    const int lane = threadIdx.x & 63;
    const int i = blockIdx.x * 4 + w;

    const unsigned pk = pos_key[i], nk = neg_key[i];
    const int pi = 8191 - (int)(pk & 8191u);
    const int ni = 8191 - (int)(nk & 8191u);
    const bool valid = (pk != 0u) && (nk != 0xFFFFFFFFu);

    const float4 av  = *reinterpret_cast<const float4*>(&emb[(size_t)i  * ND + lane * 4]);
    const float4 pvv = *reinterpret_cast<const float4*>(&emb[(size_t)pi * ND + lane * 4]);
    const float4 nvv = *reinterpret_cast<const float4*>(&emb[(size_t)ni * ND + lane * 4]);
    float sap, san;
    {
        const float d0 = av.x - pvv.x + EPS_F, d1 = av.y - pvv.y + EPS_F;
        const float d2 = av.z - pvv.z + EPS_F, d3 = av.w - pvv.w + EPS_F;
        sap = d0 * d0 + d1 * d1 + d2 * d2 + d3 * d3;
        const float e0 = av.x - nvv.x + EPS_F, e1 = av.y - nvv.y + EPS_F;
        const float e2 = av.z - nvv.z + EPS_F, e3 = av.w - nvv.w + EPS_F;
        san = e0 * e0 + e1 * e1 + e2 * e2 + e3 * e3;
    }
#pragma unroll
    for (int m = 32; m; m >>= 1) {
        sap += __shfl_down(sap, m, 64);
        san += __shfl_down(san, m, 64);
    }
    if (lane == 0) {
        const float per = fmaxf(sqrtf(sap) - sqrtf(san) + MARGIN_F, 0.0f);
        per_anc[i] = valid ? per : 0.0f;
        validf[i]  = valid ? 1.0f : 0.0f;
    }
}

// ---- final mean ----
__global__ __launch_bounds__(256) void reduce_k(const float* __restrict__ per_anc,
                                                const float* __restrict__ validf,
                                                float* __restrict__ out) {
    __shared__ float ss[4], sc[4];
    float s = 0.0f, c = 0.0f;
    for (int i = threadIdx.x; i < NB; i += 256) { s += per_anc[i]; c += validf[i]; }
#pragma unroll
    for (int m = 32; m; m >>= 1) { s += __shfl_down(s, m, 64); c += __shfl_down(c, m, 64); }
    const int w = threadIdx.x >> 6, lane = threadIdx.x & 63;
    if (lane == 0) { ss[w] = s; sc[w] = c; }
    __syncthreads();
    if (threadIdx.x == 0) {
        const float S = ss[0] + ss[1] + ss[2] + ss[3];
        const float C = sc[0] + sc[1] + sc[2] + sc[3];
        out[0] = (C > 0.0f) ? (S / fmaxf(C, 1.0f)) : 0.0f;
    }
}

extern "C" void kernel_launch(void* const* d_in, const int* in_sizes, int n_in,
                              void* d_out, int out_size, void* d_ws, size_t ws_size,
                              hipStream_t stream) {
    const float* emb = (const float*)d_in[0];
    const int* labels = (const int*)d_in[1];
    float* out = (float*)d_out;

    char* ws = (char*)d_ws;
    unsigned short* ehi = (unsigned short*)ws;                         // 4 MB packed
    float* sqnb    = (float*)(ws + (size_t)NB * ND * 2);               // 32 KB
    float* per_anc = sqnb + NB;
    float* validf  = per_anc + NB;
    unsigned int* pos_key = (unsigned int*)(validf + NB);              // 32 KB
    unsigned int* neg_key = pos_key + NB;                              // 32 KB

    hipLaunchKernelGGL(prep_k, dim3(NB / 16), dim3(512), 0, stream,
                       emb, ehi, sqnb, pos_key, neg_key);
    hipLaunchKernelGGL(pair_k, dim3(NB / 128, NSJ), dim3(256), 0, stream,
                       ehi, sqnb, labels, pos_key, neg_key);
    hipLaunchKernelGGL(finalize_k, dim3(NB / 4), dim3(256), 0, stream,
                       emb, pos_key, neg_key, per_anc, validf);
    hipLaunchKernelGGL(reduce_k, dim3(1), dim3(256), 0, stream, per_anc, validf, out);
}